// Round 1
// baseline (437.323 us; speedup 1.0000x reference)
//
#include <hip/hip_runtime.h>
#include <hip/hip_bf16.h>

// Problem constants: B=16, C=256, H=W=64, LOC=4096, DOWN=1024, C8=32, C2=128.

typedef short s8v __attribute__((ext_vector_type(8)));   // 8 x bf16 bits (4 VGPRs)
typedef float f4v __attribute__((ext_vector_type(4)));   // 4 x fp32 acc

#define MFMA16(a, b, c) __builtin_amdgcn_mfma_f32_16x16x32_bf16((a), (b), (c), 0, 0, 0)

__device__ __forceinline__ unsigned short f2b(float f) {
    __hip_bfloat16 h = __float2bfloat16(f);
    return *reinterpret_cast<unsigned short*>(&h);
}
__device__ __forceinline__ float b2f(unsigned short u) {
    union { unsigned int i; float f; } v; v.i = ((unsigned int)u) << 16; return v.f;
}

// ---------------------------------------------------------------------------
// Weight prep: concat q/k/v weights -> bf16 [192][256], bias fp32 [192],
// val2_w -> bf16 [256][128].
// ---------------------------------------------------------------------------
__global__ void prep_weights(const float* __restrict__ qw, const float* __restrict__ qb,
                             const float* __restrict__ kw, const float* __restrict__ kb,
                             const float* __restrict__ vw, const float* __restrict__ vb,
                             const float* __restrict__ v2w,
                             unsigned short* __restrict__ wqkv, float* __restrict__ bias,
                             unsigned short* __restrict__ w2b) {
    int i = blockIdx.x * 256 + threadIdx.x;
    if (i < 49152) {                       // 192*256
        int r = i >> 8, c = i & 255; float v;
        if (r < 32)       v = qw[r * 256 + c];
        else if (r < 64)  v = kw[(r - 32) * 256 + c];
        else              v = vw[(r - 64) * 256 + c];
        wqkv[i] = f2b(v);
    } else if (i < 49152 + 32768) {        // 256*128
        int k = i - 49152; w2b[k] = f2b(v2w[k]);
    } else if (i < 49152 + 32768 + 192) {
        int r = i - 49152 - 32768;
        bias[r] = (r < 32) ? qb[r] : (r < 64 ? kb[r - 32] : vb[r - 64]);
    }
}

// ---------------------------------------------------------------------------
// Generic batched transpose: src [R][C] (row-major, per batch) -> dst [C][R] bf16.
// 64x64 LDS tiles, conflict-free (pad 65).
// ---------------------------------------------------------------------------
template <typename T>
__global__ __launch_bounds__(256) void transpose_to_bf16(const T* __restrict__ src,
                                                         unsigned short* __restrict__ dst,
                                                         int R, int C) {
    __shared__ float tile[64][65];
    int b = blockIdx.z;
    size_t base = (size_t)b * R * C;
    int r0 = blockIdx.x * 64, c0 = blockIdx.y * 64;
    int tr = threadIdx.x >> 6, tc = threadIdx.x & 63;
    for (int i = 0; i < 16; ++i) {
        int rl = i * 4 + tr;
        T v = src[base + (size_t)(r0 + rl) * C + c0 + tc];
        float f;
        if constexpr (sizeof(T) == 2) f = b2f((unsigned short)v); else f = (float)v;
        tile[rl][tc] = f;
    }
    __syncthreads();
    for (int i = 0; i < 16; ++i) {
        int cl = i * 4 + tr;
        dst[base + (size_t)(c0 + cl) * R + r0 + tc] = f2b(tile[tc][cl]);
    }
}

// ---------------------------------------------------------------------------
// QKV conv GEMM: out[o,p] = sum_c Wqkv[o,c] * xbt[p,c] + bias[o].
// Block = (pchunk 64, batch). M=192 (4 waves x 48), N=64, K=256.
// o<32 -> qf (unpooled bf16 natural layout), o>=32 -> kvf scratch (unpooled).
// ---------------------------------------------------------------------------
__global__ __launch_bounds__(256) void qkv_gemm(const unsigned short* __restrict__ wqkv,
                                                const float* __restrict__ bias,
                                                const unsigned short* __restrict__ xbt,
                                                unsigned short* __restrict__ qf,
                                                unsigned short* __restrict__ kvf) {
    int b = blockIdx.y, p0 = blockIdx.x * 64;
    int wave = threadIdx.x >> 6, lane = threadIdx.x & 63;
    int m = lane & 15, quad = lane >> 4;
    const unsigned short* xb = xbt + (size_t)b * 4096 * 256;

    f4v acc[3][4] = {};
    for (int ks = 0; ks < 8; ++ks) {
        int k0 = ks * 32 + quad * 8;
        s8v afr[3], bfr[4];
        for (int mt = 0; mt < 3; ++mt)
            afr[mt] = *(const s8v*)(wqkv + (wave * 48 + mt * 16 + m) * 256 + k0);
        for (int nt = 0; nt < 4; ++nt)
            bfr[nt] = *(const s8v*)(xb + (size_t)(p0 + nt * 16 + m) * 256 + k0);
        for (int mt = 0; mt < 3; ++mt)
            for (int nt = 0; nt < 4; ++nt)
                acc[mt][nt] = MFMA16(afr[mt], bfr[nt], acc[mt][nt]);
    }
    for (int mt = 0; mt < 3; ++mt) {
        int obase = wave * 48 + mt * 16 + quad * 4;
        for (int reg = 0; reg < 4; ++reg) {
            int o = obase + reg;
            float bi = bias[o];
            for (int nt = 0; nt < 4; ++nt) {
                int p = p0 + nt * 16 + m;
                float v = acc[mt][nt][reg] + bi;
                if (o < 32) qf[(size_t)b * 131072 + o * 4096 + p] = f2b(v);
                else        kvf[(size_t)b * 655360 + (o - 32) * 4096 + p] = f2b(v);
            }
        }
    }
}

// ---------------------------------------------------------------------------
// 2x2 maxpool on kvf channels: ch<32 -> kf [32][1024], else vf [128][1024].
// ---------------------------------------------------------------------------
__global__ void pool_kv(const unsigned short* __restrict__ kvf,
                        unsigned short* __restrict__ kf, unsigned short* __restrict__ vf) {
    int idx = blockIdx.x * 256 + threadIdx.x;
    if (idx >= 16 * 160 * 1024) return;
    int b = idx / 163840;
    int rem = idx - b * 163840;
    int ch = rem >> 10, sp = rem & 1023;
    int h2 = sp >> 5, w2 = sp & 31;
    const unsigned short* s = kvf + (size_t)b * 655360 + ch * 4096 + h2 * 128 + w2 * 2;
    float a = b2f(s[0]), bb = b2f(s[1]), c = b2f(s[64]), d = b2f(s[65]);
    float mx = fmaxf(fmaxf(a, bb), fmaxf(c, d));
    if (ch < 32) kf[(size_t)b * 32768 + ch * 1024 + sp] = f2b(mx);
    else         vf[(size_t)b * 131072 + (ch - 32) * 1024 + sp] = f2b(mx);
}

// ---------------------------------------------------------------------------
// Pass A: column softmax stats. S[l,j] = dot32(qf[l,:], kf[j,:]).
// Block = (jchunk 64, batch); online (max, sumexp) over all 4096 l.
// ---------------------------------------------------------------------------
__global__ __launch_bounds__(256) void col_stats(const unsigned short* __restrict__ qf,
                                                 const unsigned short* __restrict__ kf,
                                                 float* __restrict__ mg, float* __restrict__ sg) {
    __shared__ float red[4][64][2];
    int b = blockIdx.y, j0 = blockIdx.x * 64;
    int wave = threadIdx.x >> 6, lane = threadIdx.x & 63;
    int m = lane & 15, quad = lane >> 4;
    const unsigned short* q = qf + (size_t)b * 131072;

    s8v kfr[4];
    for (int jt = 0; jt < 4; ++jt)
        kfr[jt] = *(const s8v*)(kf + (size_t)b * 32768 + (j0 + jt * 16 + m) * 32 + quad * 8);

    float mx[4] = {-1e30f, -1e30f, -1e30f, -1e30f};
    float sm[4] = {0.f, 0.f, 0.f, 0.f};
    f4v zero = {0.f, 0.f, 0.f, 0.f};

    for (int it = wave; it < 256; it += 4) {
        s8v afr = *(const s8v*)(q + (it * 16 + m) * 32 + quad * 8);
        for (int jt = 0; jt < 4; ++jt) {
            f4v sres = MFMA16(afr, kfr[jt], zero);
            for (int reg = 0; reg < 4; ++reg) {
                float v = sres[reg];
                if (v > mx[jt]) {
                    sm[jt] = sm[jt] * __expf(mx[jt] - v) + 1.0f;
                    mx[jt] = v;
                } else {
                    sm[jt] += __expf(v - mx[jt]);
                }
            }
        }
    }
    // reduce across quads (same j, different l rows)
    for (int jt = 0; jt < 4; ++jt) {
        for (int off = 16; off < 64; off <<= 1) {
            float om = __shfl_xor(mx[jt], off);
            float os = __shfl_xor(sm[jt], off);
            float nm = fmaxf(mx[jt], om);
            sm[jt] = sm[jt] * __expf(mx[jt] - nm) + os * __expf(om - nm);
            mx[jt] = nm;
        }
    }
    if (lane < 16) {
        for (int jt = 0; jt < 4; ++jt) {
            red[wave][jt * 16 + m][0] = mx[jt];
            red[wave][jt * 16 + m][1] = sm[jt];
        }
    }
    __syncthreads();
    if (threadIdx.x < 64) {
        int jj = threadIdx.x;
        float M = -1e30f, S = 0.f;
        for (int w = 0; w < 4; ++w) {
            float m_ = red[w][jj][0], s_ = red[w][jj][1];
            float nm = fmaxf(M, m_);
            S = S * __expf(M - nm) + s_ * __expf(m_ - nm);
            M = nm;
        }
        mg[b * 1024 + j0 + jj] = M;
        sg[b * 1024 + j0 + jj] = S;
    }
}

// ---------------------------------------------------------------------------
// Pass B: applied[l,c] = sum_j exp(S[l,j]-m_j)/sum_j * Vview[j,c].
// Block = (lchunk 64, batch); wave strip 16 l; P round-trips wave-private LDS.
// Vt is the transposed V-view [128 c][1024 j] bf16.
// ---------------------------------------------------------------------------
__global__ __launch_bounds__(256) void attn_pv(const unsigned short* __restrict__ qf,
                                               const unsigned short* __restrict__ kf,
                                               const unsigned short* __restrict__ vt,
                                               const float* __restrict__ mg,
                                               const float* __restrict__ sg,
                                               unsigned short* __restrict__ fa) {
    __shared__ unsigned short plds[4][16][72];   // pad 72 -> b128-aligned rows, 2-way banks
    int b = blockIdx.y, l0 = blockIdx.x * 64;
    int wave = threadIdx.x >> 6, lane = threadIdx.x & 63;
    int m = lane & 15, quad = lane >> 4;

    s8v qfr = *(const s8v*)(qf + (size_t)b * 131072 + (l0 + wave * 16 + m) * 32 + quad * 8);
    const float* mgb = mg + b * 1024;
    const float* sgb = sg + b * 1024;
    const unsigned short* kb = kf + (size_t)b * 32768;
    const unsigned short* vb = vt + (size_t)b * 131072;

    f4v acc[8] = {};
    f4v zero = {0.f, 0.f, 0.f, 0.f};

    for (int jc = 0; jc < 16; ++jc) {
        int j0 = jc * 64;
        f4v s[4];
        for (int jt = 0; jt < 4; ++jt) {
            s8v kfr = *(const s8v*)(kb + (j0 + jt * 16 + m) * 32 + quad * 8);
            s[jt] = MFMA16(qfr, kfr, zero);
        }
        for (int jt = 0; jt < 4; ++jt) {
            int j = j0 + jt * 16 + m;
            float mj = mgb[j];
            float rj = 1.0f / sgb[j];
            for (int reg = 0; reg < 4; ++reg) {
                float p = __expf(s[jt][reg] - mj) * rj;
                plds[wave][quad * 4 + reg][jt * 16 + m] = f2b(p);
            }
        }
        __threadfence_block();   // drain LDS writes before re-reading (wave-private region)
        s8v pfr0 = *(const s8v*)(&plds[wave][m][quad * 8]);
        s8v pfr1 = *(const s8v*)(&plds[wave][m][quad * 8 + 32]);
        for (int ct = 0; ct < 8; ++ct) {
            s8v vfr0 = *(const s8v*)(vb + (ct * 16 + m) * 1024 + j0 + quad * 8);
            s8v vfr1 = *(const s8v*)(vb + (ct * 16 + m) * 1024 + j0 + 32 + quad * 8);
            acc[ct] = MFMA16(pfr0, vfr0, acc[ct]);
            acc[ct] = MFMA16(pfr1, vfr1, acc[ct]);
        }
    }
    for (int ct = 0; ct < 8; ++ct)
        for (int reg = 0; reg < 4; ++reg) {
            int l = l0 + wave * 16 + quad * 4 + reg;
            fa[(size_t)b * 524288 + l * 128 + ct * 16 + m] = f2b(acc[ct][reg]);
        }
}

// ---------------------------------------------------------------------------
// Final conv + residual: out[o,p] = gamma*(sum_cc W2[o,cc]*Mview[cc,p] + b2[o]) + x.
// ga is the transposed applied-view [4096 p][128 cc] bf16.
// ---------------------------------------------------------------------------
__global__ __launch_bounds__(256) void final_gemm(const unsigned short* __restrict__ w2b,
                                                  const float* __restrict__ v2b,
                                                  const float* __restrict__ gamma,
                                                  const unsigned short* __restrict__ ga,
                                                  const float* __restrict__ x,
                                                  float* __restrict__ out) {
    int b = blockIdx.y, p0 = blockIdx.x * 64;
    int wave = threadIdx.x >> 6, lane = threadIdx.x & 63;
    int m = lane & 15, quad = lane >> 4;
    const unsigned short* gb = ga + (size_t)b * 524288;

    f4v acc[4][4] = {};
    for (int ks = 0; ks < 4; ++ks) {
        int k0 = ks * 32 + quad * 8;
        s8v afr[4], bfr[4];
        for (int mt = 0; mt < 4; ++mt)
            afr[mt] = *(const s8v*)(w2b + (wave * 64 + mt * 16 + m) * 128 + k0);
        for (int nt = 0; nt < 4; ++nt)
            bfr[nt] = *(const s8v*)(gb + (size_t)(p0 + nt * 16 + m) * 128 + k0);
        for (int mt = 0; mt < 4; ++mt)
            for (int nt = 0; nt < 4; ++nt)
                acc[mt][nt] = MFMA16(afr[mt], bfr[nt], acc[mt][nt]);
    }
    float g = gamma[0];
    for (int mt = 0; mt < 4; ++mt) {
        for (int reg = 0; reg < 4; ++reg) {
            int o = wave * 64 + mt * 16 + quad * 4 + reg;
            float bi = v2b[o];
            for (int nt = 0; nt < 4; ++nt) {
                int p = p0 + nt * 16 + m;
                size_t xi = (size_t)b * 1048576 + (size_t)o * 4096 + p;
                out[xi] = g * (acc[mt][nt][reg] + bi) + x[xi];
            }
        }
    }
}

// ---------------------------------------------------------------------------
extern "C" void kernel_launch(void* const* d_in, const int* in_sizes, int n_in,
                              void* d_out, int out_size, void* d_ws, size_t ws_size,
                              hipStream_t stream) {
    const float* x    = (const float*)d_in[0];
    const float* qw   = (const float*)d_in[1];
    const float* qb   = (const float*)d_in[2];
    const float* kw   = (const float*)d_in[3];
    const float* kb   = (const float*)d_in[4];
    const float* vw   = (const float*)d_in[5];
    const float* vb   = (const float*)d_in[6];
    const float* v2w  = (const float*)d_in[7];
    const float* v2b  = (const float*)d_in[8];
    const float* gamma = (const float*)d_in[9];
    float* out = (float*)d_out;

    char* ws = (char*)d_ws;
    size_t off = 0;
    auto alloc = [&](size_t bytes) { size_t o = off; off = (off + bytes + 255) & ~(size_t)255; return o; };
    unsigned short* wqkv = (unsigned short*)(ws + alloc(192 * 256 * 2));
    unsigned short* w2b  = (unsigned short*)(ws + alloc(256 * 128 * 2));
    float*          bias = (float*)(ws + alloc(192 * 4));
    unsigned short* xbt  = (unsigned short*)(ws + alloc((size_t)16 * 4096 * 256 * 2));   // 32 MB
    unsigned short* qf   = (unsigned short*)(ws + alloc((size_t)16 * 131072 * 2));       // 4 MB
    unsigned short* kvf  = (unsigned short*)(ws + alloc((size_t)16 * 655360 * 2));       // 20 MB
    unsigned short* kf   = (unsigned short*)(ws + alloc((size_t)16 * 32768 * 2));        // 1 MB
    unsigned short* vf   = (unsigned short*)(ws + alloc((size_t)16 * 131072 * 2));       // 4 MB
    unsigned short* vt   = (unsigned short*)(ws + alloc((size_t)16 * 131072 * 2));       // 4 MB
    float*          mgp  = (float*)(ws + alloc((size_t)16 * 1024 * 4));
    float*          sgp  = (float*)(ws + alloc((size_t)16 * 1024 * 4));
    unsigned short* fa   = (unsigned short*)(ws + alloc((size_t)16 * 524288 * 2));       // 16 MB
    unsigned short* ga   = (unsigned short*)(ws + alloc((size_t)16 * 524288 * 2));       // 16 MB
    (void)ws_size; (void)in_sizes; (void)n_in; (void)out_size;

    prep_weights<<<321, 256, 0, stream>>>(qw, qb, kw, kb, vw, vb, v2w, wqkv, bias, w2b);
    // x [256][4096] fp32 -> xbt [4096][256] bf16, per batch
    transpose_to_bf16<float><<<dim3(4, 64, 16), 256, 0, stream>>>(x, xbt, 256, 4096);
    qkv_gemm<<<dim3(64, 16), 256, 0, stream>>>(wqkv, bias, xbt, qf, kvf);
    pool_kv<<<10240, 256, 0, stream>>>(kvf, kf, vf);
    // V-view [1024][128] -> Vt [128][1024]
    transpose_to_bf16<unsigned short><<<dim3(16, 2, 16), 256, 0, stream>>>(vf, vt, 1024, 128);
    col_stats<<<dim3(16, 16), 256, 0, stream>>>(qf, kf, mgp, sgp);
    attn_pv<<<dim3(64, 16), 256, 0, stream>>>(qf, kf, vt, mgp, sgp, fa);
    // applied-view [128][4096] -> ga [4096][128]
    transpose_to_bf16<unsigned short><<<dim3(2, 64, 16), 256, 0, stream>>>(fa, ga, 128, 4096);
    final_gemm<<<dim3(64, 16), 256, 0, stream>>>(w2b, v2b, gamma, ga, x, out);
}

// Round 2
// 417.097 us; speedup vs baseline: 1.0485x; 1.0485x over previous
//
#include <hip/hip_runtime.h>
#include <hip/hip_bf16.h>

// Problem constants: B=16, C=256, H=W=64, LOC=4096, DOWN=1024, C8=32, C2=128.

typedef short s8v __attribute__((ext_vector_type(8)));   // 8 x bf16 bits (4 VGPRs)
typedef float f4v __attribute__((ext_vector_type(4)));   // 4 x fp32 acc

#define MFMA16(a, b, c) __builtin_amdgcn_mfma_f32_16x16x32_bf16((a), (b), (c), 0, 0, 0)

__device__ __forceinline__ unsigned short f2b(float f) {
    __hip_bfloat16 h = __float2bfloat16(f);
    return *reinterpret_cast<unsigned short*>(&h);
}
__device__ __forceinline__ float b2f(unsigned short u) {
    union { unsigned int i; float f; } v; v.i = ((unsigned int)u) << 16; return v.f;
}

// ---------------------------------------------------------------------------
// Weight prep: concat q/k/v weights -> bf16 [192][256], bias fp32 [192],
// val2_w -> bf16 [256][128].
// ---------------------------------------------------------------------------
__global__ void prep_weights(const float* __restrict__ qw, const float* __restrict__ qb,
                             const float* __restrict__ kw, const float* __restrict__ kb,
                             const float* __restrict__ vw, const float* __restrict__ vb,
                             const float* __restrict__ v2w,
                             unsigned short* __restrict__ wqkv, float* __restrict__ bias,
                             unsigned short* __restrict__ w2b) {
    int i = blockIdx.x * 256 + threadIdx.x;
    if (i < 49152) {                       // 192*256
        int r = i >> 8, c = i & 255; float v;
        if (r < 32)       v = qw[r * 256 + c];
        else if (r < 64)  v = kw[(r - 32) * 256 + c];
        else              v = vw[(r - 64) * 256 + c];
        wqkv[i] = f2b(v);
    } else if (i < 49152 + 32768) {        // 256*128
        int k = i - 49152; w2b[k] = f2b(v2w[k]);
    } else if (i < 49152 + 32768 + 192) {
        int r = i - 49152 - 32768;
        bias[r] = (r < 32) ? qb[r] : (r < 64 ? kb[r - 32] : vb[r - 64]);
    }
}

// ---------------------------------------------------------------------------
// Generic batched transpose: src [R][C] (row-major, per batch) -> dst [C][R] bf16.
// ---------------------------------------------------------------------------
template <typename T>
__global__ __launch_bounds__(256) void transpose_to_bf16(const T* __restrict__ src,
                                                         unsigned short* __restrict__ dst,
                                                         int R, int C) {
    __shared__ float tile[64][65];
    int b = blockIdx.z;
    size_t base = (size_t)b * R * C;
    int r0 = blockIdx.x * 64, c0 = blockIdx.y * 64;
    int tr = threadIdx.x >> 6, tc = threadIdx.x & 63;
    for (int i = 0; i < 16; ++i) {
        int rl = i * 4 + tr;
        T v = src[base + (size_t)(r0 + rl) * C + c0 + tc];
        float f;
        if constexpr (sizeof(T) == 2) f = b2f((unsigned short)v); else f = (float)v;
        tile[rl][tc] = f;
    }
    __syncthreads();
    for (int i = 0; i < 16; ++i) {
        int cl = i * 4 + tr;
        dst[base + (size_t)(c0 + cl) * R + r0 + tc] = f2b(tile[tc][cl]);
    }
}

// ---------------------------------------------------------------------------
// QKV conv GEMM: out[o,p] = sum_c Wqkv[o,c] * xbt[p,c] + bias[o].
// ---------------------------------------------------------------------------
__global__ __launch_bounds__(256) void qkv_gemm(const unsigned short* __restrict__ wqkv,
                                                const float* __restrict__ bias,
                                                const unsigned short* __restrict__ xbt,
                                                unsigned short* __restrict__ qf,
                                                unsigned short* __restrict__ kvf) {
    int b = blockIdx.y, p0 = blockIdx.x * 64;
    int wave = threadIdx.x >> 6, lane = threadIdx.x & 63;
    int m = lane & 15, quad = lane >> 4;
    const unsigned short* xb = xbt + (size_t)b * 4096 * 256;

    f4v acc[3][4] = {};
    for (int ks = 0; ks < 8; ++ks) {
        int k0 = ks * 32 + quad * 8;
        s8v afr[3], bfr[4];
        for (int mt = 0; mt < 3; ++mt)
            afr[mt] = *(const s8v*)(wqkv + (wave * 48 + mt * 16 + m) * 256 + k0);
        for (int nt = 0; nt < 4; ++nt)
            bfr[nt] = *(const s8v*)(xb + (size_t)(p0 + nt * 16 + m) * 256 + k0);
        for (int mt = 0; mt < 3; ++mt)
            for (int nt = 0; nt < 4; ++nt)
                acc[mt][nt] = MFMA16(afr[mt], bfr[nt], acc[mt][nt]);
    }
    for (int mt = 0; mt < 3; ++mt) {
        int obase = wave * 48 + mt * 16 + quad * 4;
        for (int reg = 0; reg < 4; ++reg) {
            int o = obase + reg;
            float bi = bias[o];
            for (int nt = 0; nt < 4; ++nt) {
                int p = p0 + nt * 16 + m;
                float v = acc[mt][nt][reg] + bi;
                if (o < 32) qf[(size_t)b * 131072 + o * 4096 + p] = f2b(v);
                else        kvf[(size_t)b * 655360 + (o - 32) * 4096 + p] = f2b(v);
            }
        }
    }
}

// ---------------------------------------------------------------------------
// 2x2 maxpool on kvf channels: ch<32 -> kf [32][1024], else vf [128][1024].
// ---------------------------------------------------------------------------
__global__ void pool_kv(const unsigned short* __restrict__ kvf,
                        unsigned short* __restrict__ kf, unsigned short* __restrict__ vf) {
    int idx = blockIdx.x * 256 + threadIdx.x;
    if (idx >= 16 * 160 * 1024) return;
    int b = idx / 163840;
    int rem = idx - b * 163840;
    int ch = rem >> 10, sp = rem & 1023;
    int h2 = sp >> 5, w2 = sp & 31;
    const unsigned short* s = kvf + (size_t)b * 655360 + ch * 4096 + h2 * 128 + w2 * 2;
    float a = b2f(s[0]), bb = b2f(s[1]), c = b2f(s[64]), d = b2f(s[65]);
    float mx = fmaxf(fmaxf(a, bb), fmaxf(c, d));
    if (ch < 32) kf[(size_t)b * 32768 + ch * 1024 + sp] = f2b(mx);
    else         vf[(size_t)b * 131072 + (ch - 32) * 1024 + sp] = f2b(mx);
}

// ---------------------------------------------------------------------------
// Pass A: per j-column stats + E materialization.
// Block = (j-chunk of 16, batch). Phase 1: col max via MFMA S-tiles.
// Phase 2: recompute S, write E = exp(S - m_j) bf16 row-major [l][1024],
// accumulate s_j, store rs_j = 1/s_j.
// E <= 1 always -> numerically safe; bf16 E keeps ~0.4% relative precision.
// ---------------------------------------------------------------------------
__global__ __launch_bounds__(256) void col_ep(const unsigned short* __restrict__ qf,
                                              const unsigned short* __restrict__ kf,
                                              unsigned short* __restrict__ E,
                                              float* __restrict__ rs) {
    __shared__ float mred[4][16], mfin[16], sred[4][16];
    int b = blockIdx.y, j0 = blockIdx.x * 16;
    int wave = threadIdx.x >> 6, lane = threadIdx.x & 63;
    int m = lane & 15, quad = lane >> 4;
    const unsigned short* qb = qf + (size_t)b * 131072;
    s8v kfr = *(const s8v*)(kf + (size_t)b * 32768 + (j0 + m) * 32 + quad * 8);
    f4v zero = {0.f, 0.f, 0.f, 0.f};

    // phase 1: column max
    float mx = -3e38f;
    for (int it = wave; it < 256; it += 4) {
        s8v afr = *(const s8v*)(qb + (it * 16 + m) * 32 + quad * 8);
        f4v s = MFMA16(afr, kfr, zero);
        mx = fmaxf(mx, fmaxf(fmaxf(s[0], s[1]), fmaxf(s[2], s[3])));
    }
    mx = fmaxf(mx, __shfl_xor(mx, 16));
    mx = fmaxf(mx, __shfl_xor(mx, 32));
    if (lane < 16) mred[wave][m] = mx;
    __syncthreads();
    if (threadIdx.x < 16)
        mfin[threadIdx.x] = fmaxf(fmaxf(mred[0][threadIdx.x], mred[1][threadIdx.x]),
                                  fmaxf(mred[2][threadIdx.x], mred[3][threadIdx.x]));
    __syncthreads();
    float mj = mfin[m];

    // phase 2: E = exp(S - m_j), col sum
    float sm = 0.f;
    unsigned short* Eb = E + (size_t)b * 4194304;
    for (int it = wave; it < 256; it += 4) {
        s8v afr = *(const s8v*)(qb + (it * 16 + m) * 32 + quad * 8);
        f4v s = MFMA16(afr, kfr, zero);
        float e0 = __expf(s[0] - mj), e1 = __expf(s[1] - mj);
        float e2 = __expf(s[2] - mj), e3 = __expf(s[3] - mj);
        sm += (e0 + e1) + (e2 + e3);
        unsigned short* ep = Eb + (size_t)(it * 16 + quad * 4) * 1024 + j0 + m;
        ep[0] = f2b(e0); ep[1024] = f2b(e1); ep[2048] = f2b(e2); ep[3072] = f2b(e3);
    }
    sm += __shfl_xor(sm, 16);
    sm += __shfl_xor(sm, 32);
    if (lane < 16) sred[wave][m] = sm;
    __syncthreads();
    if (threadIdx.x < 16) {
        float S = (sred[0][threadIdx.x] + sred[1][threadIdx.x]) +
                  (sred[2][threadIdx.x] + sred[3][threadIdx.x]);
        rs[b * 1024 + j0 + threadIdx.x] = 1.0f / S;
    }
}

// ---------------------------------------------------------------------------
// Fold 1/s_j into vt in place: vt[c][j] *= rs[j].
// ---------------------------------------------------------------------------
__global__ void scale_v(unsigned short* __restrict__ vt, const float* __restrict__ rs) {
    int idx = blockIdx.x * 256 + threadIdx.x;    // 262144 threads, 8 elems each
    if (idx >= 262144) return;
    int e0 = idx * 8;
    int b = e0 >> 17;                            // 131072 elems per batch
    int j = e0 & 1023;
    const float4* rp = (const float4*)(rs + b * 1024 + j);
    float4 r0 = rp[0], r1 = rp[1];
    s8v v = *(s8v*)(vt + e0);
    s8v o;
    o[0] = (short)f2b(b2f((unsigned short)v[0]) * r0.x);
    o[1] = (short)f2b(b2f((unsigned short)v[1]) * r0.y);
    o[2] = (short)f2b(b2f((unsigned short)v[2]) * r0.z);
    o[3] = (short)f2b(b2f((unsigned short)v[3]) * r0.w);
    o[4] = (short)f2b(b2f((unsigned short)v[4]) * r1.x);
    o[5] = (short)f2b(b2f((unsigned short)v[5]) * r1.y);
    o[6] = (short)f2b(b2f((unsigned short)v[6]) * r1.z);
    o[7] = (short)f2b(b2f((unsigned short)v[7]) * r1.w);
    *(s8v*)(vt + e0) = o;
}

// ---------------------------------------------------------------------------
// Pass B: pure bf16 GEMM. applied[l,c] = sum_j E[l,j] * Vscaled[c,j].
// Block = 64 l x 128 c (wave = 32 l x 64 c); K = 1024.
// ---------------------------------------------------------------------------
__global__ __launch_bounds__(256) void pv_gemm(const unsigned short* __restrict__ E,
                                               const unsigned short* __restrict__ vs,
                                               unsigned short* __restrict__ fa) {
    int b = blockIdx.y, l0 = blockIdx.x * 64;
    int wave = threadIdx.x >> 6, lane = threadIdx.x & 63;
    int m = lane & 15, quad = lane >> 4;
    int lhalf = wave >> 1, chalf = wave & 1;
    const unsigned short* Eb = E + (size_t)b * 4194304 + (size_t)(l0 + lhalf * 32) * 1024;
    const unsigned short* vb = vs + (size_t)b * 131072 + (size_t)(chalf * 64) * 1024;

    f4v acc[2][4] = {};
    for (int jc = 0; jc < 32; ++jc) {
        int j0 = jc * 32 + quad * 8;
        s8v a0 = *(const s8v*)(Eb + (size_t)m * 1024 + j0);
        s8v a1 = *(const s8v*)(Eb + (size_t)(16 + m) * 1024 + j0);
        for (int ct = 0; ct < 4; ++ct) {
            s8v bf = *(const s8v*)(vb + (size_t)(ct * 16 + m) * 1024 + j0);
            acc[0][ct] = MFMA16(a0, bf, acc[0][ct]);
            acc[1][ct] = MFMA16(a1, bf, acc[1][ct]);
        }
    }
    for (int lt = 0; lt < 2; ++lt)
        for (int ct = 0; ct < 4; ++ct)
            for (int reg = 0; reg < 4; ++reg) {
                int l = l0 + lhalf * 32 + lt * 16 + quad * 4 + reg;
                int c = chalf * 64 + ct * 16 + m;
                fa[(size_t)b * 524288 + (size_t)l * 128 + c] = f2b(acc[lt][ct][reg]);
            }
}

// ---------------------------------------------------------------------------
// Final conv + residual: out[o,p] = gamma*(sum_cc W2[o,cc]*Mview[cc,p] + b2[o]) + x.
// ---------------------------------------------------------------------------
__global__ __launch_bounds__(256) void final_gemm(const unsigned short* __restrict__ w2b,
                                                  const float* __restrict__ v2b,
                                                  const float* __restrict__ gamma,
                                                  const unsigned short* __restrict__ ga,
                                                  const float* __restrict__ x,
                                                  float* __restrict__ out) {
    int b = blockIdx.y, p0 = blockIdx.x * 64;
    int wave = threadIdx.x >> 6, lane = threadIdx.x & 63;
    int m = lane & 15, quad = lane >> 4;
    const unsigned short* gb = ga + (size_t)b * 524288;

    f4v acc[4][4] = {};
    for (int ks = 0; ks < 4; ++ks) {
        int k0 = ks * 32 + quad * 8;
        s8v afr[4], bfr[4];
        for (int mt = 0; mt < 4; ++mt)
            afr[mt] = *(const s8v*)(w2b + (wave * 64 + mt * 16 + m) * 128 + k0);
        for (int nt = 0; nt < 4; ++nt)
            bfr[nt] = *(const s8v*)(gb + (size_t)(p0 + nt * 16 + m) * 128 + k0);
        for (int mt = 0; mt < 4; ++mt)
            for (int nt = 0; nt < 4; ++nt)
                acc[mt][nt] = MFMA16(afr[mt], bfr[nt], acc[mt][nt]);
    }
    float g = gamma[0];
    for (int mt = 0; mt < 4; ++mt) {
        for (int reg = 0; reg < 4; ++reg) {
            int o = wave * 64 + mt * 16 + quad * 4 + reg;
            float bi = v2b[o];
            for (int nt = 0; nt < 4; ++nt) {
                int p = p0 + nt * 16 + m;
                size_t xi = (size_t)b * 1048576 + (size_t)o * 4096 + p;
                out[xi] = g * (acc[mt][nt][reg] + bi) + x[xi];
            }
        }
    }
}

// ---------------------------------------------------------------------------
extern "C" void kernel_launch(void* const* d_in, const int* in_sizes, int n_in,
                              void* d_out, int out_size, void* d_ws, size_t ws_size,
                              hipStream_t stream) {
    const float* x    = (const float*)d_in[0];
    const float* qw   = (const float*)d_in[1];
    const float* qb   = (const float*)d_in[2];
    const float* kw   = (const float*)d_in[3];
    const float* kb   = (const float*)d_in[4];
    const float* vw   = (const float*)d_in[5];
    const float* vb   = (const float*)d_in[6];
    const float* v2w  = (const float*)d_in[7];
    const float* v2b  = (const float*)d_in[8];
    const float* gamma = (const float*)d_in[9];
    float* out = (float*)d_out;

    char* ws = (char*)d_ws;
    size_t off = 0;
    auto alloc = [&](size_t bytes) { size_t o = off; off = (off + bytes + 255) & ~(size_t)255; return o; };
    unsigned short* wqkv = (unsigned short*)(ws + alloc(192 * 256 * 2));
    unsigned short* w2b  = (unsigned short*)(ws + alloc(256 * 128 * 2));
    float*          bias = (float*)(ws + alloc(192 * 4));
    float*          rs   = (float*)(ws + alloc((size_t)16 * 1024 * 4));
    unsigned short* qf   = (unsigned short*)(ws + alloc((size_t)16 * 131072 * 2));       // 4 MB
    unsigned short* kf   = (unsigned short*)(ws + alloc((size_t)16 * 32768 * 2));        // 1 MB
    unsigned short* vf   = (unsigned short*)(ws + alloc((size_t)16 * 131072 * 2));       // 4 MB
    unsigned short* vt   = (unsigned short*)(ws + alloc((size_t)16 * 131072 * 2));       // 4 MB (scaled in place)
    unsigned short* fa   = (unsigned short*)(ws + alloc((size_t)16 * 524288 * 2));       // 16 MB
    char*           Ebase = ws + alloc((size_t)16 * 4194304 * 2);                        // 128 MB
    unsigned short* E    = (unsigned short*)Ebase;
    // Overlays inside E region (lifetimes end before col_ep writes E):
    unsigned short* xbt  = (unsigned short*)Ebase;                 // 32 MB, dead after qkv_gemm
    unsigned short* kvf  = (unsigned short*)(Ebase + 33554432);    // 20 MB, dead after pool_kv
    unsigned short* ga   = (unsigned short*)Ebase;                 // 16 MB, written after pv_gemm reads E
    (void)ws_size; (void)in_sizes; (void)n_in; (void)out_size;

    prep_weights<<<321, 256, 0, stream>>>(qw, qb, kw, kb, vw, vb, v2w, wqkv, bias, w2b);
    // x [256][4096] fp32 -> xbt [4096][256] bf16, per batch
    transpose_to_bf16<float><<<dim3(4, 64, 16), 256, 0, stream>>>(x, xbt, 256, 4096);
    qkv_gemm<<<dim3(64, 16), 256, 0, stream>>>(wqkv, bias, xbt, qf, kvf);
    pool_kv<<<10240, 256, 0, stream>>>(kvf, kf, vf);
    // V-view [1024][128] -> vt [128][1024]
    transpose_to_bf16<unsigned short><<<dim3(16, 2, 16), 256, 0, stream>>>(vf, vt, 1024, 128);
    col_ep<<<dim3(64, 16), 256, 0, stream>>>(qf, kf, E, rs);
    scale_v<<<1024, 256, 0, stream>>>(vt, rs);
    pv_gemm<<<dim3(64, 16), 256, 0, stream>>>(E, vt, fa);
    // applied-view [128][4096] -> ga [4096][128]
    transpose_to_bf16<unsigned short><<<dim3(2, 64, 16), 256, 0, stream>>>(fa, ga, 128, 4096);
    final_gemm<<<dim3(64, 16), 256, 0, stream>>>(w2b, v2b, gamma, ga, x, out);
}

// Round 3
// 370.607 us; speedup vs baseline: 1.1800x; 1.1254x over previous
//
#include <hip/hip_runtime.h>
#include <hip/hip_bf16.h>

// Problem constants: B=16, C=256, H=W=64, LOC=4096, DOWN=1024, C8=32, C2=128.

typedef short s8v __attribute__((ext_vector_type(8)));   // 8 x bf16 bits (4 VGPRs)
typedef float f4v __attribute__((ext_vector_type(4)));   // 4 x fp32 acc

#define MFMA16(a, b, c) __builtin_amdgcn_mfma_f32_16x16x32_bf16((a), (b), (c), 0, 0, 0)

__device__ __forceinline__ unsigned short f2b(float f) {
    __hip_bfloat16 h = __float2bfloat16(f);
    return *reinterpret_cast<unsigned short*>(&h);
}
__device__ __forceinline__ float b2f(unsigned short u) {
    union { unsigned int i; float f; } v; v.i = ((unsigned int)u) << 16; return v.f;
}

// ---------------------------------------------------------------------------
// Weight prep: concat q/k/v weights -> bf16 [192][256], bias fp32 [192],
// val2_w -> bf16 [256][128].
// ---------------------------------------------------------------------------
__global__ void prep_weights(const float* __restrict__ qw, const float* __restrict__ qb,
                             const float* __restrict__ kw, const float* __restrict__ kb,
                             const float* __restrict__ vw, const float* __restrict__ vb,
                             const float* __restrict__ v2w,
                             unsigned short* __restrict__ wqkv, float* __restrict__ bias,
                             unsigned short* __restrict__ w2b) {
    int i = blockIdx.x * 256 + threadIdx.x;
    if (i < 49152) {                       // 192*256
        int r = i >> 8, c = i & 255; float v;
        if (r < 32)       v = qw[r * 256 + c];
        else if (r < 64)  v = kw[(r - 32) * 256 + c];
        else              v = vw[(r - 64) * 256 + c];
        wqkv[i] = f2b(v);
    } else if (i < 49152 + 32768) {        // 256*128
        int k = i - 49152; w2b[k] = f2b(v2w[k]);
    } else if (i < 49152 + 32768 + 192) {
        int r = i - 49152 - 32768;
        bias[r] = (r < 32) ? qb[r] : (r < 64 ? kb[r - 32] : vb[r - 64]);
    }
}

// ---------------------------------------------------------------------------
// Generic batched transpose: src [R][C] (row-major, per batch) -> dst [C][R] bf16.
// ---------------------------------------------------------------------------
template <typename T>
__global__ __launch_bounds__(256) void transpose_to_bf16(const T* __restrict__ src,
                                                         unsigned short* __restrict__ dst,
                                                         int R, int C) {
    __shared__ float tile[64][65];
    int b = blockIdx.z;
    size_t base = (size_t)b * R * C;
    int r0 = blockIdx.x * 64, c0 = blockIdx.y * 64;
    int tr = threadIdx.x >> 6, tc = threadIdx.x & 63;
    for (int i = 0; i < 16; ++i) {
        int rl = i * 4 + tr;
        T v = src[base + (size_t)(r0 + rl) * C + c0 + tc];
        float f;
        if constexpr (sizeof(T) == 2) f = b2f((unsigned short)v); else f = (float)v;
        tile[rl][tc] = f;
    }
    __syncthreads();
    for (int i = 0; i < 16; ++i) {
        int cl = i * 4 + tr;
        dst[base + (size_t)(c0 + cl) * R + r0 + tc] = f2b(tile[tc][cl]);
    }
}

// ---------------------------------------------------------------------------
// QKV conv GEMM with fused 2x2 maxpool for K/V.
// Block: M=192 (4 waves x 48 o), N=128 p (= one h-row pair). K=256.
// q (o<32) -> qf [32][4096] natural; k -> kf [32][1024] pooled; v -> vf [128][1024].
// ---------------------------------------------------------------------------
__global__ __launch_bounds__(256) void qkv_pool(const unsigned short* __restrict__ wqkv,
                                                const float* __restrict__ bias,
                                                const unsigned short* __restrict__ xbt,
                                                unsigned short* __restrict__ qf,
                                                unsigned short* __restrict__ kf,
                                                unsigned short* __restrict__ vf) {
    int b = blockIdx.y, r = blockIdx.x;      // r = h-pair index, p0 = 128*r
    int p0 = r * 128;
    int wave = threadIdx.x >> 6, lane = threadIdx.x & 63;
    int m = lane & 15, quad = lane >> 4;
    const unsigned short* xb = xbt + (size_t)b * 4096 * 256;

    f4v acc[3][8] = {};
    for (int ks = 0; ks < 8; ++ks) {
        int k0 = ks * 32 + quad * 8;
        s8v afr[3];
        for (int mt = 0; mt < 3; ++mt)
            afr[mt] = *(const s8v*)(wqkv + (wave * 48 + mt * 16 + m) * 256 + k0);
        for (int nt = 0; nt < 8; ++nt) {
            s8v bfr = *(const s8v*)(xb + (size_t)(p0 + nt * 16 + m) * 256 + k0);
            for (int mt = 0; mt < 3; ++mt)
                acc[mt][nt] = MFMA16(afr[mt], bfr, acc[mt][nt]);
        }
    }
    for (int mt = 0; mt < 3; ++mt) {
        int obase = wave * 48 + mt * 16;     // 16-aligned: tile entirely q, k, or v
        if (obase < 32) {
            // query: write all 128 p, natural layout
            for (int reg = 0; reg < 4; ++reg) {
                int o = obase + quad * 4 + reg;
                float bi = bias[o];
                for (int nt = 0; nt < 8; ++nt)
                    qf[(size_t)b * 131072 + (size_t)o * 4096 + p0 + nt * 16 + m] =
                        f2b(acc[mt][nt][reg] + bi);
            }
        } else {
            // key/value: 2x2 maxpool then write
            for (int reg = 0; reg < 4; ++reg) {
                int o = obase + quad * 4 + reg;
                float bi = bias[o];
                for (int nt = 0; nt < 4; ++nt) {
                    float vv = fmaxf(acc[mt][nt][reg], acc[mt][nt + 4][reg]); // h, h+1
                    float ov = __shfl_xor(vv, 1);                             // w pair
                    if ((m & 1) == 0) {
                        float res = fmaxf(vv, ov) + bi;
                        int w2 = nt * 8 + (m >> 1);
                        int sp = r * 32 + w2;
                        if (o < 64) kf[(size_t)b * 32768 + (size_t)(o - 32) * 1024 + sp] = f2b(res);
                        else        vf[(size_t)b * 131072 + (size_t)(o - 64) * 1024 + sp] = f2b(res);
                    }
                }
            }
        }
    }
}

// ---------------------------------------------------------------------------
// Column softmax stats: m_j (max over l) and rs_j = 1/sum_l exp(S-m_j).
// Two-phase S recompute via MFMA. Block = (64 j, batch), grid (16,16).
// ---------------------------------------------------------------------------
__global__ __launch_bounds__(256) void col_stats2(const unsigned short* __restrict__ qf,
                                                  const unsigned short* __restrict__ kf,
                                                  float* __restrict__ mg, float* __restrict__ rs) {
    __shared__ float red[4][64];
    int b = blockIdx.y, j0 = blockIdx.x * 64;
    int wave = threadIdx.x >> 6, lane = threadIdx.x & 63;
    int m = lane & 15, quad = lane >> 4;
    const unsigned short* qb = qf + (size_t)b * 131072;
    f4v zero = {0.f, 0.f, 0.f, 0.f};

    s8v kfr[4];
    for (int jt = 0; jt < 4; ++jt)
        kfr[jt] = *(const s8v*)(kf + (size_t)b * 32768 + (size_t)(j0 + jt * 16 + m) * 32 + quad * 8);

    float mx[4] = {-3e38f, -3e38f, -3e38f, -3e38f};
    for (int it = wave; it < 256; it += 4) {
        s8v afr = *(const s8v*)(qb + (size_t)(it * 16 + m) * 32 + quad * 8);
        for (int jt = 0; jt < 4; ++jt) {
            f4v s = MFMA16(afr, kfr[jt], zero);
            mx[jt] = fmaxf(mx[jt], fmaxf(fmaxf(s[0], s[1]), fmaxf(s[2], s[3])));
        }
    }
    for (int jt = 0; jt < 4; ++jt) {
        mx[jt] = fmaxf(mx[jt], __shfl_xor(mx[jt], 16));
        mx[jt] = fmaxf(mx[jt], __shfl_xor(mx[jt], 32));
    }
    if (lane < 16)
        for (int jt = 0; jt < 4; ++jt) red[wave][jt * 16 + m] = mx[jt];
    __syncthreads();
    if (threadIdx.x < 64) {
        int t = threadIdx.x;
        float M = fmaxf(fmaxf(red[0][t], red[1][t]), fmaxf(red[2][t], red[3][t]));
        mg[b * 1024 + j0 + t] = M;
        red[0][t] = M;
    }
    __syncthreads();
    float mj[4];
    for (int jt = 0; jt < 4; ++jt) mj[jt] = red[0][jt * 16 + m];

    float sm[4] = {0.f, 0.f, 0.f, 0.f};
    for (int it = wave; it < 256; it += 4) {
        s8v afr = *(const s8v*)(qb + (size_t)(it * 16 + m) * 32 + quad * 8);
        for (int jt = 0; jt < 4; ++jt) {
            f4v s = MFMA16(afr, kfr[jt], zero);
            sm[jt] += (__expf(s[0] - mj[jt]) + __expf(s[1] - mj[jt])) +
                      (__expf(s[2] - mj[jt]) + __expf(s[3] - mj[jt]));
        }
    }
    for (int jt = 0; jt < 4; ++jt) {
        sm[jt] += __shfl_xor(sm[jt], 16);
        sm[jt] += __shfl_xor(sm[jt], 32);
    }
    __syncthreads();
    if (lane < 16)
        for (int jt = 0; jt < 4; ++jt) red[wave][jt * 16 + m] = sm[jt];
    __syncthreads();
    if (threadIdx.x < 64) {
        int t = threadIdx.x;
        float S = (red[0][t] + red[1][t]) + (red[2][t] + red[3][t]);
        rs[b * 1024 + j0 + t] = 1.0f / S;
    }
}

// ---------------------------------------------------------------------------
// Fold 1/s_j into vt in place: vt[c][j] *= rs[j].
// ---------------------------------------------------------------------------
__global__ void scale_v(unsigned short* __restrict__ vt, const float* __restrict__ rs) {
    int idx = blockIdx.x * 256 + threadIdx.x;    // 262144 threads, 8 elems each
    if (idx >= 262144) return;
    int e0 = idx * 8;
    int b = e0 >> 17;                            // 131072 elems per batch
    int j = e0 & 1023;
    const float4* rp = (const float4*)(rs + b * 1024 + j);
    float4 r0 = rp[0], r1 = rp[1];
    s8v v = *(s8v*)(vt + e0);
    s8v o;
    o[0] = (short)f2b(b2f((unsigned short)v[0]) * r0.x);
    o[1] = (short)f2b(b2f((unsigned short)v[1]) * r0.y);
    o[2] = (short)f2b(b2f((unsigned short)v[2]) * r0.z);
    o[3] = (short)f2b(b2f((unsigned short)v[3]) * r0.w);
    o[4] = (short)f2b(b2f((unsigned short)v[4]) * r1.x);
    o[5] = (short)f2b(b2f((unsigned short)v[5]) * r1.y);
    o[6] = (short)f2b(b2f((unsigned short)v[6]) * r1.z);
    o[7] = (short)f2b(b2f((unsigned short)v[7]) * r1.w);
    *(s8v*)(vt + e0) = o;
}

// ---------------------------------------------------------------------------
// Fused attention: recompute S tile-wise, P = exp(S - m_j), C->A layout via
// wave-private LDS rows, PV against pre-scaled V. Block = 128 l x 128 c.
// No __syncthreads: each wave owns PL rows [32w, 32w+32).
// ---------------------------------------------------------------------------
__global__ __launch_bounds__(256, 4) void attn_fused(const unsigned short* __restrict__ qf,
                                                     const unsigned short* __restrict__ kf,
                                                     const unsigned short* __restrict__ vs,
                                                     const float* __restrict__ mg,
                                                     unsigned short* __restrict__ fa) {
    __shared__ unsigned short PL[128][136];   // 34.8 KB; b128-aligned rows
    int b = blockIdx.y, l0 = blockIdx.x * 128;
    int wave = threadIdx.x >> 6, lane = threadIdx.x & 63;
    int m = lane & 15, quad = lane >> 4;
    const unsigned short* qb = qf + (size_t)b * 131072;
    const unsigned short* kb = kf + (size_t)b * 32768;
    const unsigned short* vb = vs + (size_t)b * 131072;
    const float* mb = mg + b * 1024;
    int strip = wave * 32;

    s8v qa[2];
    for (int lt = 0; lt < 2; ++lt)
        qa[lt] = *(const s8v*)(qb + (size_t)(l0 + strip + lt * 16 + m) * 32 + quad * 8);

    f4v acc[2][8] = {};
    f4v zero = {0.f, 0.f, 0.f, 0.f};

    for (int jc = 0; jc < 8; ++jc) {
        int j0 = jc * 128;
        for (int jt = 0; jt < 8; ++jt) {
            s8v kfr = *(const s8v*)(kb + (size_t)(j0 + jt * 16 + m) * 32 + quad * 8);
            float mj = mb[j0 + jt * 16 + m];
            for (int lt = 0; lt < 2; ++lt) {
                f4v s = MFMA16(qa[lt], kfr, zero);
                int row = strip + lt * 16 + quad * 4;
                for (int reg = 0; reg < 4; ++reg)
                    PL[row + reg][jt * 16 + m] = f2b(__expf(s[reg] - mj));
            }
        }
        __threadfence_block();   // order LDS writes before reads (wave-private rows)
        for (int ks = 0; ks < 4; ++ks) {
            s8v pa[2];
            pa[0] = *(const s8v*)(&PL[strip + m][ks * 32 + quad * 8]);
            pa[1] = *(const s8v*)(&PL[strip + 16 + m][ks * 32 + quad * 8]);
            for (int ct = 0; ct < 8; ++ct) {
                s8v vfr = *(const s8v*)(vb + (size_t)(ct * 16 + m) * 1024 + j0 + ks * 32 + quad * 8);
                acc[0][ct] = MFMA16(pa[0], vfr, acc[0][ct]);
                acc[1][ct] = MFMA16(pa[1], vfr, acc[1][ct]);
            }
        }
        __threadfence_block();   // reads done before next chunk's writes (WAR)
    }
    for (int lt = 0; lt < 2; ++lt)
        for (int ct = 0; ct < 8; ++ct)
            for (int reg = 0; reg < 4; ++reg) {
                int l = l0 + strip + lt * 16 + quad * 4 + reg;
                fa[(size_t)b * 524288 + (size_t)l * 128 + ct * 16 + m] = f2b(acc[lt][ct][reg]);
            }
}

// ---------------------------------------------------------------------------
// Final conv + residual: out[o,p] = gamma*(sum_cc W2[o,cc]*Mview[cc,p] + b2[o]) + x.
// ---------------------------------------------------------------------------
__global__ __launch_bounds__(256) void final_gemm(const unsigned short* __restrict__ w2b,
                                                  const float* __restrict__ v2b,
                                                  const float* __restrict__ gamma,
                                                  const unsigned short* __restrict__ ga,
                                                  const float* __restrict__ x,
                                                  float* __restrict__ out) {
    int b = blockIdx.y, p0 = blockIdx.x * 64;
    int wave = threadIdx.x >> 6, lane = threadIdx.x & 63;
    int m = lane & 15, quad = lane >> 4;
    const unsigned short* gb = ga + (size_t)b * 524288;

    f4v acc[4][4] = {};
    for (int ks = 0; ks < 4; ++ks) {
        int k0 = ks * 32 + quad * 8;
        s8v afr[4], bfr[4];
        for (int mt = 0; mt < 4; ++mt)
            afr[mt] = *(const s8v*)(w2b + (wave * 64 + mt * 16 + m) * 128 + k0);
        for (int nt = 0; nt < 4; ++nt)
            bfr[nt] = *(const s8v*)(gb + (size_t)(p0 + nt * 16 + m) * 128 + k0);
        for (int mt = 0; mt < 4; ++mt)
            for (int nt = 0; nt < 4; ++nt)
                acc[mt][nt] = MFMA16(afr[mt], bfr[nt], acc[mt][nt]);
    }
    float g = gamma[0];
    for (int mt = 0; mt < 4; ++mt) {
        for (int reg = 0; reg < 4; ++reg) {
            int o = wave * 64 + mt * 16 + quad * 4 + reg;
            float bi = v2b[o];
            for (int nt = 0; nt < 4; ++nt) {
                int p = p0 + nt * 16 + m;
                size_t xi = (size_t)b * 1048576 + (size_t)o * 4096 + p;
                out[xi] = g * (acc[mt][nt][reg] + bi) + x[xi];
            }
        }
    }
}

// ---------------------------------------------------------------------------
extern "C" void kernel_launch(void* const* d_in, const int* in_sizes, int n_in,
                              void* d_out, int out_size, void* d_ws, size_t ws_size,
                              hipStream_t stream) {
    const float* x    = (const float*)d_in[0];
    const float* qw   = (const float*)d_in[1];
    const float* qb   = (const float*)d_in[2];
    const float* kw   = (const float*)d_in[3];
    const float* kb   = (const float*)d_in[4];
    const float* vw   = (const float*)d_in[5];
    const float* vb   = (const float*)d_in[6];
    const float* v2w  = (const float*)d_in[7];
    const float* v2b  = (const float*)d_in[8];
    const float* gamma = (const float*)d_in[9];
    float* out = (float*)d_out;

    char* ws = (char*)d_ws;
    size_t off = 0;
    auto alloc = [&](size_t bytes) { size_t o = off; off = (off + bytes + 255) & ~(size_t)255; return o; };
    unsigned short* wqkv = (unsigned short*)(ws + alloc(192 * 256 * 2));
    unsigned short* w2b  = (unsigned short*)(ws + alloc(256 * 128 * 2));
    float*          bias = (float*)(ws + alloc(192 * 4));
    float*          mgp  = (float*)(ws + alloc((size_t)16 * 1024 * 4));
    float*          rs   = (float*)(ws + alloc((size_t)16 * 1024 * 4));
    unsigned short* qf   = (unsigned short*)(ws + alloc((size_t)16 * 131072 * 2));       // 4 MB
    unsigned short* kf   = (unsigned short*)(ws + alloc((size_t)16 * 32768 * 2));        // 1 MB
    unsigned short* vf   = (unsigned short*)(ws + alloc((size_t)16 * 131072 * 2));       // 4 MB
    unsigned short* vt   = (unsigned short*)(ws + alloc((size_t)16 * 131072 * 2));       // 4 MB (scaled in place)
    unsigned short* fa   = (unsigned short*)(ws + alloc((size_t)16 * 524288 * 2));       // 16 MB
    char*           big  = ws + alloc((size_t)16 * 4096 * 256 * 2);                      // 32 MB shared
    unsigned short* xbt  = (unsigned short*)big;                    // dead after qkv_pool
    unsigned short* ga   = (unsigned short*)big;                    // written after
    (void)ws_size; (void)in_sizes; (void)n_in; (void)out_size;

    prep_weights<<<321, 256, 0, stream>>>(qw, qb, kw, kb, vw, vb, v2w, wqkv, bias, w2b);
    // x [256][4096] fp32 -> xbt [4096][256] bf16, per batch
    transpose_to_bf16<float><<<dim3(4, 64, 16), 256, 0, stream>>>(x, xbt, 256, 4096);
    qkv_pool<<<dim3(32, 16), 256, 0, stream>>>(wqkv, bias, xbt, qf, kf, vf);
    // V raw view [1024][128] -> vt [128][1024]
    transpose_to_bf16<unsigned short><<<dim3(16, 2, 16), 256, 0, stream>>>(vf, vt, 1024, 128);
    col_stats2<<<dim3(16, 16), 256, 0, stream>>>(qf, kf, mgp, rs);
    scale_v<<<1024, 256, 0, stream>>>(vt, rs);
    attn_fused<<<dim3(32, 16), 256, 0, stream>>>(qf, kf, vt, mgp, fa);
    // applied raw view [128][4096] -> ga [4096][128]
    transpose_to_bf16<unsigned short><<<dim3(2, 64, 16), 256, 0, stream>>>(fa, ga, 128, 4096);
    final_gemm<<<dim3(64, 16), 256, 0, stream>>>(w2b, v2b, gamma, ga, x, out);
}